// Round 6
// baseline (24.692 us; speedup 1.0000x reference)
//
#include <hip/hip_runtime.h>
#include <cmath>

#define IMG_H 1080
#define IMG_W 1920
#define NPIX (IMG_H * IMG_W)     // 2,073,600
#define BLOCK 64                 // one wave per block: barrier is intra-wave
#define PXT 8                    // pixels per thread (8 | 1920 -> no row cross)
#define PXB (BLOCK * PXT)        // 512 pixels per block
#define NBLOCKS (NPIX / PXB)     // 4050 exact
#define NXCD 8

typedef __attribute__((ext_vector_type(4))) float f32x4;

__global__ __launch_bounds__(BLOCK) void pose_fwd_kernel(
    const float* __restrict__ x,
    const float* __restrict__ ref_img,
    const float* __restrict__ ref_depth,
    const float* __restrict__ trg_img,
    const float* __restrict__ K,
    float* __restrict__ out)
{
    __shared__ float sout[PXB * 7];     // 14 KB output transpose staging

    const int tid = threadIdx.x;

    // ---- bijective XCD-aware block swizzle (m204). NBLOCKS=4050: q=506, r=2.
    const int orig = blockIdx.x;
    const int xcd  = orig % NXCD;
    const int idx  = orig / NXCD;
    const int q_   = NBLOCKS / NXCD;
    const int r_   = NBLOCKS % NXCD;
    const int blk  = (xcd < r_ ? xcd * (q_ + 1) : r_ * (q_ + 1) + (xcd - r_) * q_) + idx;

    const int n0 = blk * PXB + tid * PXT;            // group of 8 consecutive px
    const int v  = n0 / IMG_W;
    const int u0 = n0 - v * IMG_W;

    // ---- se3_exp(x): computed redundantly by every thread ----
    float R0, R1, R2, R3, R4, R5, R6, R7, R8, tx, ty, tz;
    {
        const float wx = x[0], wy = x[1], wz = x[2];
        const float vx = x[3], vy = x[4], vz = x[5];
        const float t2 = wx * wx + wy * wy + wz * wz;
        float A, B, C;
        if (t2 < 1e-8f) {
            A = 1.0f - t2 / 6.0f;
            B = 0.5f - t2 / 24.0f;
            C = 1.0f / 6.0f - t2 / 120.0f;
        } else {
            const float th = sqrtf(t2);
            const float s = sinf(th), c = cosf(th);
            A = s / th;
            B = (1.0f - c) / t2;
            C = (th - s) / (t2 * th);
        }
        const float W00 = -(wy * wy + wz * wz), W01 = wx * wy, W02 = wx * wz;
        const float W11 = -(wx * wx + wz * wz), W12 = wy * wz;
        const float W22 = -(wx * wx + wy * wy);
        R0 = 1.0f + B * W00;        R1 = A * (-wz) + B * W01;  R2 = A * wy + B * W02;
        R3 = A * wz + B * W01;      R4 = 1.0f + B * W11;       R5 = A * (-wx) + B * W12;
        R6 = A * (-wy) + B * W02;   R7 = A * wx + B * W12;     R8 = 1.0f + B * W22;
        const float V00 = 1.0f + C * W00,      V01 = B * (-wz) + C * W01, V02 = B * wy + C * W02;
        const float V10 = B * wz + C * W01,    V11 = 1.0f + C * W11,      V12 = B * (-wx) + C * W12;
        const float V20 = B * (-wy) + C * W02, V21 = B * wx + C * W12,    V22 = 1.0f + C * W22;
        tx = V00 * vx + V01 * vy + V02 * vz;
        ty = V10 * vx + V11 * vy + V12 * vz;
        tz = V20 * vx + V21 * vy + V22 * vz;
    }

    // intrinsics (uniform)
    const float k00 = K[0], k01 = K[1], k02 = K[2];
    const float k10 = K[3], k11 = K[4], k12 = K[5];
    const float k20 = K[6], k21 = K[7], k22 = K[8];
    const float fx = k00, fy = k11, cx = k02, cy = k12;
    const float inv_fx = __builtin_amdgcn_rcpf(fx);
    const float inv_fy = __builtin_amdgcn_rcpf(fy);

    // ---- vector loads: depth (8 px = 2 x f32x4) ----
    const f32x4 dz4a = *(const f32x4*)(ref_depth + n0);
    const f32x4 dz4b = *(const f32x4*)(ref_depth + n0 + 4);
    const float zs[8] = {dz4a.x, dz4a.y, dz4a.z, dz4a.w,
                         dz4b.x, dz4b.y, dz4b.z, dz4b.w};

    // ---- Sobel 3x10 neighborhood (cols u0-1 .. u0+8) via 4 chunks/row ----
    const int rm1 = (v > 0)         ? v - 1 : 0;
    const int rp1 = (v < IMG_H - 1) ? v + 1 : IMG_H - 1;
    const int cl  = (u0 > 0)             ? u0 - 4 : 0;          // covers u0-1
    const int cr  = (u0 + 12 <= IMG_W)   ? u0 + 8 : IMG_W - 4;  // covers u0+8

    const float* rtop = trg_img + (size_t)rm1 * IMG_W;
    const float* rmid = trg_img + (size_t)v   * IMG_W;
    const float* rbot = trg_img + (size_t)rp1 * IMG_W;

    const f32x4 tA = *(const f32x4*)(rtop + cl);
    const f32x4 tB = *(const f32x4*)(rtop + u0);
    const f32x4 tC = *(const f32x4*)(rtop + u0 + 4);
    const f32x4 tD = *(const f32x4*)(rtop + cr);
    const f32x4 mA = *(const f32x4*)(rmid + cl);
    const f32x4 mB = *(const f32x4*)(rmid + u0);
    const f32x4 mC = *(const f32x4*)(rmid + u0 + 4);
    const f32x4 mD = *(const f32x4*)(rmid + cr);
    const f32x4 bA = *(const f32x4*)(rbot + cl);
    const f32x4 bB = *(const f32x4*)(rbot + u0);
    const f32x4 bC = *(const f32x4*)(rbot + u0 + 4);
    const f32x4 bD = *(const f32x4*)(rbot + cr);

    // index k <-> column u0-1+k, k = 0..9
    const float top[10] = {tA.w, tB.x, tB.y, tB.z, tB.w, tC.x, tC.y, tC.z, tC.w, tD.x};
    const float mid[10] = {mA.w, mB.x, mB.y, mB.z, mB.w, mC.x, mC.y, mC.z, mC.w, mD.x};
    const float bot[10] = {bA.w, bB.x, bB.y, bB.z, bB.w, bC.x, bC.y, bC.z, bC.w, bD.x};

    const bool vok = (v >= 2) && (v <= IMG_H - 3);
    const float vf = (float)v;

    float out_local[PXT * 7];

#pragma unroll
    for (int j = 0; j < PXT; ++j) {
        const float z = zs[j];
        const float uf = (float)(u0 + j);
        const float X = (uf - cx) * z * inv_fx;
        const float Y = (vf - cy) * z * inv_fy;

        // p = R @ pts + t
        const float px = fmaf(R0, X, fmaf(R1, Y, fmaf(R2, z, tx)));
        const float py = fmaf(R3, X, fmaf(R4, Y, fmaf(R5, z, ty)));
        const float pz = fmaf(R6, X, fmaf(R7, Y, fmaf(R8, z, tz)));

        // proj = K @ p
        const float p0 = fmaf(k00, px, fmaf(k01, py, k02 * pz));
        const float p1 = fmaf(k10, px, fmaf(k11, py, k12 * pz));
        const float p2 = fmaf(k20, px, fmaf(k21, py, k22 * pz));

        const float rp2 = __builtin_amdgcn_rcpf(p2);
        const float uw = p0 * rp2;
        const float vw = p1 * rp2;
        const int ui = (int)uw;     // trunc toward zero == astype(int32)
        const int vi = (int)vw;
        const bool valid = (vi < IMG_H) && (ui < IMG_W) && (vi > 0) && (ui > 0);
        const int cu = min(max(ui, 0), IMG_W - 1);
        const int cv = min(max(vi, 0), IMG_H - 1);
        const float warped = ref_img[cv * IMG_W + cu];
        const float res = valid ? (warped - mid[j + 1]) : 0.0f;

        // Sobel (borders zeroed)
        float gx = 0.0f, gy = 0.0f;
        if (vok && (u0 + j >= 2) && (u0 + j <= IMG_W - 3)) {
            gx = 0.125f * (top[j + 2] - top[j]) + 0.25f * (mid[j + 2] - mid[j])
               + 0.125f * (bot[j + 2] - bot[j]);
            gy = 0.125f * (bot[j] - top[j]) + 0.25f * (bot[j + 1] - top[j + 1])
               + 0.125f * (bot[j + 2] - top[j + 2]);
        }

        // J = gx * r0 + gy * r1 (reference uses fx in BOTH rows)
        float J0 = 0.0f, J1 = 0.0f, J2 = 0.0f, J3 = 0.0f, J4 = 0.0f, J5 = 0.0f;
        if (valid) {
            const float zi  = __builtin_amdgcn_rcpf(z);
            const float zi2 = zi * zi;
            const float xy  = X * Y * zi2;
            const float gxfx = gx * fx, gyfx = gy * fx;
            J0 = -gxfx * xy - gyfx * fmaf(Y * Y, zi2, 1.0f);
            J1 =  gxfx * fmaf(X * X, zi2, 1.0f) + gyfx * xy;
            J2 = (gyfx * X - gxfx * Y) * zi;
            J3 =  gxfx * zi;
            J4 =  gyfx * zi;
            J5 = -(gxfx * X + gyfx * Y) * zi2;
        }

        out_local[j * 7 + 0] = res;
        out_local[j * 7 + 1] = J0;
        out_local[j * 7 + 2] = J1;
        out_local[j * 7 + 3] = J2;
        out_local[j * 7 + 4] = J3;
        out_local[j * 7 + 5] = J4;
        out_local[j * 7 + 6] = J5;
    }

    // ---- intra-wave LDS transpose: 14 b128 writes (stride-14, worst 2-way
    // = free), then 14 fully-coalesced 1KB global stores ----
    f32x4* sout4 = (f32x4*)sout;
#pragma unroll
    for (int q = 0; q < 14; ++q) {
        f32x4 t;
        t.x = out_local[q * 4 + 0]; t.y = out_local[q * 4 + 1];
        t.z = out_local[q * 4 + 2]; t.w = out_local[q * 4 + 3];
        sout4[tid * 14 + q] = t;
    }
    __syncthreads();

    const f32x4* src4 = (const f32x4*)sout;
    f32x4* out4 = (f32x4*)out + (size_t)blk * (PXB * 7 / 4);
#pragma unroll
    for (int q = 0; q < 14; ++q) {
        out4[q * BLOCK + tid] = src4[q * BLOCK + tid];
    }
}

extern "C" void kernel_launch(void* const* d_in, const int* in_sizes, int n_in,
                              void* d_out, int out_size, void* d_ws, size_t ws_size,
                              hipStream_t stream) {
    const float* x          = (const float*)d_in[0];
    const float* ref_img    = (const float*)d_in[1];
    const float* ref_depth  = (const float*)d_in[2];
    const float* trg_img    = (const float*)d_in[3];
    const float* intrinsics = (const float*)d_in[4];
    float* out = (float*)d_out;

    pose_fwd_kernel<<<NBLOCKS, BLOCK, 0, stream>>>(
        x, ref_img, ref_depth, trg_img, intrinsics, out);
}

// Round 7
// 19.432 us; speedup vs baseline: 1.2707x; 1.2707x over previous
//
#include <hip/hip_runtime.h>
#include <cmath>

#define IMG_H 1080
#define IMG_W 1920
#define NPIX (IMG_H * IMG_W)     // 2,073,600
#define BLOCK 64                 // one wave per block: barrier is intra-wave
#define PXT 4                    // pixels per thread
#define PXB (BLOCK * PXT)        // 256 pixels per block
#define NBLOCKS (NPIX / PXB)     // 8100 exact
#define NXCD 8

typedef __attribute__((ext_vector_type(4))) float f32x4;

__global__ __launch_bounds__(BLOCK) void pose_fwd_kernel(
    const float* __restrict__ x,
    const float* __restrict__ ref_img,
    const float* __restrict__ ref_depth,
    const float* __restrict__ trg_img,
    const float* __restrict__ K,
    float* __restrict__ out)
{
    __shared__ float sout[PXB * 7];     // 7 KB output transpose staging

    const int tid = threadIdx.x;

    // ---- bijective XCD-aware block swizzle (m204). NBLOCKS=8100: q=1012, r=4.
    const int orig = blockIdx.x;
    const int xcd  = orig % NXCD;
    const int idx  = orig / NXCD;
    const int q_   = NBLOCKS / NXCD;
    const int r_   = NBLOCKS % NXCD;
    const int blk  = (xcd < r_ ? xcd * (q_ + 1) : r_ * (q_ + 1) + (xcd - r_) * q_) + idx;

    const int n0 = blk * PXB + tid * PXT;            // group of 4 consecutive px
    const int v  = n0 / IMG_W;                       // W%4==0 -> group never crosses row
    const int u0 = n0 - v * IMG_W;

    // ---- se3_exp(x): computed redundantly by every thread (uniform scalar
    // loads + ~60 VALU once per thread) ----
    float R0, R1, R2, R3, R4, R5, R6, R7, R8, tx, ty, tz;
    {
        const float wx = x[0], wy = x[1], wz = x[2];
        const float vx = x[3], vy = x[4], vz = x[5];
        const float t2 = wx * wx + wy * wy + wz * wz;
        float A, B, C;
        if (t2 < 1e-8f) {
            A = 1.0f - t2 / 6.0f;
            B = 0.5f - t2 / 24.0f;
            C = 1.0f / 6.0f - t2 / 120.0f;
        } else {
            const float th = sqrtf(t2);
            const float s = sinf(th), c = cosf(th);
            A = s / th;
            B = (1.0f - c) / t2;
            C = (th - s) / (t2 * th);
        }
        const float W00 = -(wy * wy + wz * wz), W01 = wx * wy, W02 = wx * wz;
        const float W11 = -(wx * wx + wz * wz), W12 = wy * wz;
        const float W22 = -(wx * wx + wy * wy);
        R0 = 1.0f + B * W00;        R1 = A * (-wz) + B * W01;  R2 = A * wy + B * W02;
        R3 = A * wz + B * W01;      R4 = 1.0f + B * W11;       R5 = A * (-wx) + B * W12;
        R6 = A * (-wy) + B * W02;   R7 = A * wx + B * W12;     R8 = 1.0f + B * W22;
        const float V00 = 1.0f + C * W00,      V01 = B * (-wz) + C * W01, V02 = B * wy + C * W02;
        const float V10 = B * wz + C * W01,    V11 = 1.0f + C * W11,      V12 = B * (-wx) + C * W12;
        const float V20 = B * (-wy) + C * W02, V21 = B * wx + C * W12,    V22 = 1.0f + C * W22;
        tx = V00 * vx + V01 * vy + V02 * vz;
        ty = V10 * vx + V11 * vy + V12 * vz;
        tz = V20 * vx + V21 * vy + V22 * vz;
    }

    // intrinsics (uniform)
    const float k00 = K[0], k01 = K[1], k02 = K[2];
    const float k10 = K[3], k11 = K[4], k12 = K[5];
    const float k20 = K[6], k21 = K[7], k22 = K[8];
    const float fx = k00, fy = k11, cx = k02, cy = k12;
    const float inv_fx = __builtin_amdgcn_rcpf(fx);
    const float inv_fy = __builtin_amdgcn_rcpf(fy);

    // ---- vector loads: depth (4 px) + Sobel 3x6 neighborhood ----
    const f32x4 dz4 = *(const f32x4*)(ref_depth + n0);
    const float zs[4] = {dz4.x, dz4.y, dz4.z, dz4.w};

    const int rm1 = (v > 0)         ? v - 1 : 0;
    const int rp1 = (v < IMG_H - 1) ? v + 1 : IMG_H - 1;
    const int cl  = (u0 > 0)            ? u0 - 4 : 0;          // left chunk col
    const int cr  = (u0 + 8 <= IMG_W)   ? u0 + 4 : IMG_W - 4;  // right chunk col

    const float* rtop = trg_img + (size_t)rm1 * IMG_W;
    const float* rmid = trg_img + (size_t)v   * IMG_W;
    const float* rbot = trg_img + (size_t)rp1 * IMG_W;

    const float4 ta = *(const float4*)(rtop + cl);
    const float4 tb = *(const float4*)(rtop + u0);
    const float4 tc = *(const float4*)(rtop + cr);
    const float4 ma = *(const float4*)(rmid + cl);
    const float4 mb = *(const float4*)(rmid + u0);
    const float4 mc = *(const float4*)(rmid + cr);
    const float4 ba = *(const float4*)(rbot + cl);
    const float4 bb = *(const float4*)(rbot + u0);
    const float4 bc = *(const float4*)(rbot + cr);

    const float top[6] = {ta.w, tb.x, tb.y, tb.z, tb.w, tc.x};
    const float mid[6] = {ma.w, mb.x, mb.y, mb.z, mb.w, mc.x};
    const float bot[6] = {ba.w, bb.x, bb.y, bb.z, bb.w, bc.x};

    const bool vok = (v >= 2) && (v <= IMG_H - 3);
    const float vf = (float)v;

    float out_local[28];

#pragma unroll
    for (int j = 0; j < PXT; ++j) {
        const float z = zs[j];
        const float uf = (float)(u0 + j);
        const float X = (uf - cx) * z * inv_fx;
        const float Y = (vf - cy) * z * inv_fy;

        // p = R @ pts + t
        const float px = fmaf(R0, X, fmaf(R1, Y, fmaf(R2, z, tx)));
        const float py = fmaf(R3, X, fmaf(R4, Y, fmaf(R5, z, ty)));
        const float pz = fmaf(R6, X, fmaf(R7, Y, fmaf(R8, z, tz)));

        // proj = K @ p
        const float p0 = fmaf(k00, px, fmaf(k01, py, k02 * pz));
        const float p1 = fmaf(k10, px, fmaf(k11, py, k12 * pz));
        const float p2 = fmaf(k20, px, fmaf(k21, py, k22 * pz));

        const float rp2 = __builtin_amdgcn_rcpf(p2);
        const float uw = p0 * rp2;
        const float vw = p1 * rp2;
        const int ui = (int)uw;     // trunc toward zero == astype(int32)
        const int vi = (int)vw;
        const bool valid = (vi < IMG_H) && (ui < IMG_W) && (vi > 0) && (ui > 0);
        const int cu = min(max(ui, 0), IMG_W - 1);
        const int cv = min(max(vi, 0), IMG_H - 1);
        const float warped = ref_img[cv * IMG_W + cu];
        const float res = valid ? (warped - mid[j + 1]) : 0.0f;

        // Sobel (borders zeroed)
        float gx = 0.0f, gy = 0.0f;
        if (vok && (u0 + j >= 2) && (u0 + j <= IMG_W - 3)) {
            gx = 0.125f * (top[j + 2] - top[j]) + 0.25f * (mid[j + 2] - mid[j])
               + 0.125f * (bot[j + 2] - bot[j]);
            gy = 0.125f * (bot[j] - top[j]) + 0.25f * (bot[j + 1] - top[j + 1])
               + 0.125f * (bot[j + 2] - top[j + 2]);
        }

        // J = gx * r0 + gy * r1 (reference uses fx in BOTH rows)
        float J0 = 0.0f, J1 = 0.0f, J2 = 0.0f, J3 = 0.0f, J4 = 0.0f, J5 = 0.0f;
        if (valid) {
            const float zi  = __builtin_amdgcn_rcpf(z);
            const float zi2 = zi * zi;
            const float xy  = X * Y * zi2;
            const float gxfx = gx * fx, gyfx = gy * fx;
            J0 = -gxfx * xy - gyfx * fmaf(Y * Y, zi2, 1.0f);
            J1 =  gxfx * fmaf(X * X, zi2, 1.0f) + gyfx * xy;
            J2 = (gyfx * X - gxfx * Y) * zi;
            J3 =  gxfx * zi;
            J4 =  gyfx * zi;
            J5 = -(gxfx * X + gyfx * Y) * zi2;
        }

        out_local[j * 7 + 0] = res;
        out_local[j * 7 + 1] = J0;
        out_local[j * 7 + 2] = J1;
        out_local[j * 7 + 3] = J2;
        out_local[j * 7 + 4] = J3;
        out_local[j * 7 + 5] = J4;
        out_local[j * 7 + 6] = J5;
    }

    // ---- intra-wave LDS transpose (barrier couples only this wave) ----
    f32x4* sout4 = (f32x4*)sout;
#pragma unroll
    for (int q = 0; q < 7; ++q) {
        f32x4 t;
        t.x = out_local[q * 4 + 0]; t.y = out_local[q * 4 + 1];
        t.z = out_local[q * 4 + 2]; t.w = out_local[q * 4 + 3];
        sout4[tid * 7 + q] = t;
    }
    __syncthreads();

    const f32x4* src4 = (const f32x4*)sout;
    f32x4* out4 = (f32x4*)out + (size_t)blk * (PXB * 7 / 4);
#pragma unroll
    for (int q = 0; q < 7; ++q) {
        // output is write-once, never read: evict-first so the 58MB stream
        // doesn't churn trg rows out of L2 (isolated NT-stores-only probe)
        __builtin_nontemporal_store(src4[q * BLOCK + tid], out4 + q * BLOCK + tid);
    }
}

extern "C" void kernel_launch(void* const* d_in, const int* in_sizes, int n_in,
                              void* d_out, int out_size, void* d_ws, size_t ws_size,
                              hipStream_t stream) {
    const float* x          = (const float*)d_in[0];
    const float* ref_img    = (const float*)d_in[1];
    const float* ref_depth  = (const float*)d_in[2];
    const float* trg_img    = (const float*)d_in[3];
    const float* intrinsics = (const float*)d_in[4];
    float* out = (float*)d_out;

    pose_fwd_kernel<<<NBLOCKS, BLOCK, 0, stream>>>(
        x, ref_img, ref_depth, trg_img, intrinsics, out);
}